// Round 1
// baseline (380.745 us; speedup 1.0000x reference)
//
#include <hip/hip_runtime.h>

// TemporalEmbedding: out = concat(emb0[i0], emb1[i1], emb2[i2], pe) @ W + b
// Restructured as table precompute (tiny GEMMs) + gather-add (memory-bound).
//
// Workspace layout (floats):
//   T0 at 0        : 7   x 512
//   T1 at 7*512    : 24  x 512
//   T2 at 31*512   : 288 x 512
//   Tp at 319*512  : 2048x 512   (includes bias b)
// Total (319+2048)*512 floats = 4.85 MB.

#define TILE 64
#define TKK  16

__global__ __launch_bounds__(256) void te_table_gemm(
    const float* __restrict__ emb0, const float* __restrict__ emb1,
    const float* __restrict__ emb2, const float* __restrict__ pe,
    const float* __restrict__ W, const float* __restrict__ bias,
    float* __restrict__ T)
{
    // grid: x = 8 N-tiles (512/64), y = 39 M-tiles (1 + 1 + 5 + 32)
    __shared__ float As[TKK][TILE + 4];   // [k][m], stride 68 floats (16B-aligned rows)
    __shared__ float Bs[TKK][TILE + 4];   // [k][n]

    const int nt  = blockIdx.x;
    const int mt  = blockIdx.y;
    const int tid = threadIdx.x;

    const float* A; int M; int m0; int wrow; float* outp; bool addb;
    if (mt == 0)      { A = emb0; M = 7;    m0 = 0;              wrow = 0;    outp = T;           addb = false; }
    else if (mt == 1) { A = emb1; M = 24;   m0 = 0;              wrow = 512;  outp = T + 7*512;   addb = false; }
    else if (mt < 7)  { A = emb2; M = 288;  m0 = (mt - 2)*TILE;  wrow = 1024; outp = T + 31*512;  addb = false; }
    else              { A = pe;   M = 2048; m0 = (mt - 7)*TILE;  wrow = 1536; outp = T + 319*512; addb = true;  }

    const int n0 = nt * TILE;

    // staging coords
    const int ar = tid >> 2;          // 0..63 : A-tile row
    const int ac = (tid & 3) * 4;     // k offset (float4)
    const int br = tid >> 4;          // 0..15 : B-tile k row
    const int bc = (tid & 15) * 4;    // n offset (float4)

    // compute coords: each thread -> 4x4 outputs
    const int my = (tid >> 4) * 4;    // 0..60
    const int mx = (tid & 15) * 4;    // 0..60

    float acc[4][4];
    #pragma unroll
    for (int i = 0; i < 4; i++)
        #pragma unroll
        for (int j = 0; j < 4; j++) acc[i][j] = 0.f;

    for (int k0 = 0; k0 < 512; k0 += TKK) {
        float4 av = make_float4(0.f, 0.f, 0.f, 0.f);
        if (m0 + ar < M)
            av = *(const float4*)&A[(size_t)(m0 + ar) * 512 + k0 + ac];
        float4 bv = *(const float4*)&W[(size_t)(wrow + k0 + br) * 512 + n0 + bc];

        __syncthreads();   // previous iteration's reads complete
        As[ac + 0][ar] = av.x;
        As[ac + 1][ar] = av.y;
        As[ac + 2][ar] = av.z;
        As[ac + 3][ar] = av.w;
        *(float4*)&Bs[br][bc] = bv;
        __syncthreads();

        #pragma unroll
        for (int k = 0; k < TKK; k++) {
            float4 a4 = *(const float4*)&As[k][my];
            float4 b4 = *(const float4*)&Bs[k][mx];
            acc[0][0] += a4.x * b4.x; acc[0][1] += a4.x * b4.y; acc[0][2] += a4.x * b4.z; acc[0][3] += a4.x * b4.w;
            acc[1][0] += a4.y * b4.x; acc[1][1] += a4.y * b4.y; acc[1][2] += a4.y * b4.z; acc[1][3] += a4.y * b4.w;
            acc[2][0] += a4.z * b4.x; acc[2][1] += a4.z * b4.y; acc[2][2] += a4.z * b4.z; acc[2][3] += a4.z * b4.w;
            acc[3][0] += a4.w * b4.x; acc[3][1] += a4.w * b4.y; acc[3][2] += a4.w * b4.z; acc[3][3] += a4.w * b4.w;
        }
    }

    float4 bb = make_float4(0.f, 0.f, 0.f, 0.f);
    if (addb) bb = *(const float4*)&bias[n0 + mx];

    #pragma unroll
    for (int i = 0; i < 4; i++) {
        int row = m0 + my + i;
        if (row < M) {
            float4 v;
            v.x = acc[i][0] + bb.x;
            v.y = acc[i][1] + bb.y;
            v.z = acc[i][2] + bb.z;
            v.w = acc[i][3] + bb.w;
            *(float4*)&outp[(size_t)row * 512 + n0 + mx] = v;
        }
    }
}

// out[o, b, l, d] = T0[idx0[b,l], d] + T1[idx1[b,l], d] + T2[idx2[b,l], d] + Tp[l, d]
// One thread per float4 (4 consecutive d).
__global__ __launch_bounds__(256) void te_gather_add(
    const int* __restrict__ in0, const int* __restrict__ tg0,
    const int* __restrict__ in1, const int* __restrict__ tg1,
    const int* __restrict__ in2, const int* __restrict__ tg2,
    const float* __restrict__ T, float* __restrict__ out)
{
    const int gid = blockIdx.x * 256 + threadIdx.x;  // 0 .. 16,777,215
    const int d4  = gid & 127;        // which float4 of the 512-dim row
    const int row = gid >> 7;         // 0 .. 131071
    const int l   = row & 2047;
    const int bl  = row & 65535;      // b*2048 + l
    const int o   = row >> 16;        // 0 = input encode, 1 = target encode

    const int* __restrict__ p0 = o ? tg0 : in0;
    const int* __restrict__ p1 = o ? tg1 : in1;
    const int* __restrict__ p2 = o ? tg2 : in2;
    const int i0 = p0[bl];
    const int i1 = p1[bl];
    const int i2 = p2[bl];

    const float4* __restrict__ T0 = (const float4*)T;                // 7   x 128 float4
    const float4* __restrict__ T1 = (const float4*)(T + 7 * 512);    // 24  x 128
    const float4* __restrict__ T2 = (const float4*)(T + 31 * 512);   // 288 x 128
    const float4* __restrict__ Tp = (const float4*)(T + 319 * 512);  // 2048x 128

    const float4 a = T0[i0 * 128 + d4];
    const float4 b = T1[i1 * 128 + d4];
    const float4 c = T2[i2 * 128 + d4];
    const float4 p = Tp[l  * 128 + d4];

    float4 r;
    r.x = a.x + b.x + c.x + p.x;
    r.y = a.y + b.y + c.y + p.y;
    r.z = a.z + b.z + c.z + p.z;
    r.w = a.w + b.w + c.w + p.w;

    ((float4*)out)[gid] = r;
}

extern "C" void kernel_launch(void* const* d_in, const int* in_sizes, int n_in,
                              void* d_out, int out_size, void* d_ws, size_t ws_size,
                              hipStream_t stream) {
    const int*   in0  = (const int*)  d_in[0];
    const int*   tg0  = (const int*)  d_in[1];
    const int*   in1  = (const int*)  d_in[2];
    const int*   tg1  = (const int*)  d_in[3];
    const int*   in2  = (const int*)  d_in[4];
    const int*   tg2  = (const int*)  d_in[5];
    const float* emb0 = (const float*)d_in[6];
    const float* emb1 = (const float*)d_in[7];
    const float* emb2 = (const float*)d_in[8];
    const float* pe   = (const float*)d_in[9];
    const float* W    = (const float*)d_in[10];
    const float* bias = (const float*)d_in[11];
    float* out = (float*)d_out;
    float* T   = (float*)d_ws;   // needs (319+2048)*512*4 = 4.85 MB

    // 1) precompute projected tables
    dim3 ggrid(8, 39);
    te_table_gemm<<<ggrid, 256, 0, stream>>>(emb0, emb1, emb2, pe, W, bias, T);

    // 2) gather-add into both outputs (2*32*2048*512 floats = 16,777,216 float4)
    te_gather_add<<<65536, 256, 0, stream>>>(in0, tg0, in1, tg1, in2, tg2, T, out);
}

// Round 3
// 359.055 us; speedup vs baseline: 1.0604x; 1.0604x over previous
//
#include <hip/hip_runtime.h>

// TemporalEmbedding: out = concat(emb0[i0], emb1[i1], emb2[i2], pe) @ W + b
// Restructured as: split-K table GEMM (partials) -> reduce(+bias) -> gather-add.
//
// T row layout (2367 rows x 512):
//   rows 0..6     : T0 = emb0 @ W[0:512]
//   rows 7..30    : T1 = emb1 @ W[512:1024]
//   rows 31..318  : T2 = emb2 @ W[1024:1536]
//   rows 319..2366: Tp = pe[:2048] @ W[1536:2048] + b
//
// Workspace (floats):
//   T at 0                 : 2367 x 512            (4.85 MB)
//   P at 2367*512          : 4 x 2367 x 512        (19.4 MB)  split-K partials

#define TM 32
#define TN 64
#define TK 16
#define KSPLIT 4
#define TROWS 2367

// clang-native vector type for __builtin_nontemporal_store
typedef float vfloat4 __attribute__((ext_vector_type(4)));

__global__ __launch_bounds__(256) void te_gemm_partial(
    const float* __restrict__ emb0, const float* __restrict__ emb1,
    const float* __restrict__ emb2, const float* __restrict__ pe,
    const float* __restrict__ W, float* __restrict__ P)
{
    // grid: x = 8 n-tiles, y = 75 m-tiles (1 + 1 + 9 + 64), z = 4 k-splits
    __shared__ float As[TK][TM + 4];   // [k][m]
    __shared__ float Bs[TK][TN + 4];   // [k][n]

    const int nt  = blockIdx.x;
    const int mt  = blockIdx.y;
    const int kz  = blockIdx.z;
    const int tid = threadIdx.x;

    const float* A; int M; int m0; int wrow; int tbase;
    if (mt == 0)       { A = emb0; M = 7;    m0 = 0;            wrow = 0;    tbase = 0;   }
    else if (mt == 1)  { A = emb1; M = 24;   m0 = 0;            wrow = 512;  tbase = 7;   }
    else if (mt < 11)  { A = emb2; M = 288;  m0 = (mt-2)*TM;    wrow = 1024; tbase = 31;  }
    else               { A = pe;   M = 2048; m0 = (mt-11)*TM;   wrow = 1536; tbase = 319; }

    const int n0 = nt * TN;
    const int kbase = kz * 128;   // this block's K range: [kbase, kbase+128)

    // staging coords
    const int ar = tid >> 2;          // 0..63 (only 0..31 used for A rows)
    const int ac = (tid & 3) * 4;     // k offset (float4)
    const int br = tid >> 4;          // 0..15 : B k-row
    const int bc = (tid & 15) * 4;    // n offset (float4)

    // compute coords: 2x4 outputs per thread
    const int my = (tid >> 4) * 2;    // 0..30
    const int mx = (tid & 15) * 4;    // 0..60

    float acc[2][4];
    #pragma unroll
    for (int i = 0; i < 2; i++)
        #pragma unroll
        for (int j = 0; j < 4; j++) acc[i][j] = 0.f;

    for (int k0 = 0; k0 < 128; k0 += TK) {
        float4 av = make_float4(0.f, 0.f, 0.f, 0.f);
        if (ar < TM && (m0 + ar) < M)
            av = *(const float4*)&A[(size_t)(m0 + ar) * 512 + kbase + k0 + ac];
        float4 bv = *(const float4*)&W[(size_t)(wrow + kbase + k0 + br) * 512 + n0 + bc];

        __syncthreads();
        if (ar < TM) {
            As[ac + 0][ar] = av.x;
            As[ac + 1][ar] = av.y;
            As[ac + 2][ar] = av.z;
            As[ac + 3][ar] = av.w;
        }
        *(float4*)&Bs[br][bc] = bv;
        __syncthreads();

        #pragma unroll
        for (int k = 0; k < TK; k++) {
            float2 a2 = *(const float2*)&As[k][my];
            float4 b4 = *(const float4*)&Bs[k][mx];
            acc[0][0] += a2.x * b4.x; acc[0][1] += a2.x * b4.y;
            acc[0][2] += a2.x * b4.z; acc[0][3] += a2.x * b4.w;
            acc[1][0] += a2.y * b4.x; acc[1][1] += a2.y * b4.y;
            acc[1][2] += a2.y * b4.z; acc[1][3] += a2.y * b4.w;
        }
    }

    #pragma unroll
    for (int i = 0; i < 2; i++) {
        int row = m0 + my + i;
        if (row < M) {
            *(float4*)&P[((size_t)kz * TROWS + tbase + row) * 512 + n0 + mx] =
                make_float4(acc[i][0], acc[i][1], acc[i][2], acc[i][3]);
        }
    }
}

// T[idx] = sum_kz P[kz][idx]  (+ bias for pe rows)
__global__ __launch_bounds__(256) void te_reduce(
    const float* __restrict__ P, const float* __restrict__ bias,
    float* __restrict__ T)
{
    const int idx4 = blockIdx.x * 256 + threadIdx.x;   // float4 index, < 302976
    if (idx4 >= TROWS * 128) return;
    const int row = idx4 >> 7;
    const int d4  = idx4 & 127;

    const float4* P4 = (const float4*)P;
    const size_t stride4 = (size_t)TROWS * 128;
    float4 s = P4[idx4];
    #pragma unroll
    for (int kz = 1; kz < KSPLIT; kz++) {
        float4 v = P4[kz * stride4 + idx4];
        s.x += v.x; s.y += v.y; s.z += v.z; s.w += v.w;
    }
    if (row >= 319) {
        float4 bb = ((const float4*)bias)[d4];
        s.x += bb.x; s.y += bb.y; s.z += bb.z; s.w += bb.w;
    }
    ((float4*)T)[idx4] = s;
}

// out[o, b, l, :] = T0[idx0[b,l]] + T1[idx1[b,l]] + T2[idx2[b,l]] + Tp[l]
__global__ __launch_bounds__(256) void te_gather_add(
    const int* __restrict__ in0, const int* __restrict__ tg0,
    const int* __restrict__ in1, const int* __restrict__ tg1,
    const int* __restrict__ in2, const int* __restrict__ tg2,
    const float* __restrict__ T, float* __restrict__ out)
{
    const int gid = blockIdx.x * 256 + threadIdx.x;  // 0 .. 16,777,215
    const int d4  = gid & 127;
    const int row = gid >> 7;
    const int l   = row & 2047;
    const int bl  = row & 65535;
    const int o   = row >> 16;

    const int* __restrict__ p0 = o ? tg0 : in0;
    const int* __restrict__ p1 = o ? tg1 : in1;
    const int* __restrict__ p2 = o ? tg2 : in2;
    const int i0 = p0[bl];
    const int i1 = p1[bl];
    const int i2 = p2[bl];

    const float4* __restrict__ T0 = (const float4*)T;                // 7    x 128
    const float4* __restrict__ T1 = (const float4*)(T + 7 * 512);    // 24   x 128
    const float4* __restrict__ T2 = (const float4*)(T + 31 * 512);   // 288  x 128
    const float4* __restrict__ Tp = (const float4*)(T + 319 * 512);  // 2048 x 128

    const float4 a = T0[i0 * 128 + d4];
    const float4 b = T1[i1 * 128 + d4];
    const float4 c = T2[i2 * 128 + d4];
    const float4 p = Tp[l  * 128 + d4];

    vfloat4 r;
    r.x = a.x + b.x + c.x + p.x;
    r.y = a.y + b.y + c.y + p.y;
    r.z = a.z + b.z + c.z + p.z;
    r.w = a.w + b.w + c.w + p.w;

    // Non-temporal: keep the 268 MB output stream from evicting T out of L2.
    __builtin_nontemporal_store(r, ((vfloat4*)out) + gid);
}

extern "C" void kernel_launch(void* const* d_in, const int* in_sizes, int n_in,
                              void* d_out, int out_size, void* d_ws, size_t ws_size,
                              hipStream_t stream) {
    const int*   in0  = (const int*)  d_in[0];
    const int*   tg0  = (const int*)  d_in[1];
    const int*   in1  = (const int*)  d_in[2];
    const int*   tg1  = (const int*)  d_in[3];
    const int*   in2  = (const int*)  d_in[4];
    const int*   tg2  = (const int*)  d_in[5];
    const float* emb0 = (const float*)d_in[6];
    const float* emb1 = (const float*)d_in[7];
    const float* emb2 = (const float*)d_in[8];
    const float* pe   = (const float*)d_in[9];
    const float* W    = (const float*)d_in[10];
    const float* bias = (const float*)d_in[11];
    float* out = (float*)d_out;
    float* T   = (float*)d_ws;                      // 2367 x 512
    float* P   = T + (size_t)TROWS * 512;           // 4 x 2367 x 512

    // 1) split-K partial GEMMs for the projected tables
    dim3 ggrid(8, 75, KSPLIT);
    te_gemm_partial<<<ggrid, 256, 0, stream>>>(emb0, emb1, emb2, pe, W, P);

    // 2) reduce partials (+ bias into Tp rows)
    te_reduce<<<(TROWS * 128 + 255) / 256, 256, 0, stream>>>(P, bias, T);

    // 3) gather-add into both outputs
    te_gather_add<<<65536, 256, 0, stream>>>(in0, tg0, in1, tg1, in2, tg2, T, out);
}